// Round 1
// baseline (113.007 us; speedup 1.0000x reference)
//
#include <hip/hip_runtime.h>
#include <hip/hip_bf16.h>

#define NN 4096
#define FF 512
#define RR 64
#define HH 8
#define CAP 512

// ---------------------------------------------------------------------------
// K1: hidden[h][n][r] = sum_f X[n][f] * W[h][f][r]
// block = 256 threads, computes 64 rows x 64 cols (full R) for one head.
// Each thread: 4x4 accumulator, BK=32 K-tiles staged in LDS.
// ---------------------------------------------------------------------------
__global__ __launch_bounds__(256) void k_gemm_hidden(
    const float* __restrict__ X,
    const float* __restrict__ W,
    float* __restrict__ hidden)
{
  const int h = blockIdx.y;
  const int row0 = blockIdx.x * 64;
  __shared__ float As[32][68];  // [k][n], padded to 68 for aligned float4 reads
  __shared__ float Bs[32][64];  // [k][r]
  const int tid = threadIdx.x;
  const int tx = tid & 15;   // col group (4 cols)
  const int ty = tid >> 4;   // row group (4 rows)
  float acc[4][4] = {{0.f, 0.f, 0.f, 0.f}, {0.f, 0.f, 0.f, 0.f},
                     {0.f, 0.f, 0.f, 0.f}, {0.f, 0.f, 0.f, 0.f}};
  const float* Wh = W + (size_t)h * FF * RR;

  for (int k0 = 0; k0 < FF; k0 += 32) {
    // stage A tile (64 rows x 32 k), transposed into As[k][n]
#pragma unroll
    for (int v = 0; v < 2; ++v) {
      int idx = tid + v * 256;      // 0..511 float4s
      int n = idx >> 3;             // 0..63
      int k = (idx & 7) << 2;       // 0,4,...,28
      const float4 val =
          *reinterpret_cast<const float4*>(&X[(size_t)(row0 + n) * FF + k0 + k]);
      As[k + 0][n] = val.x;
      As[k + 1][n] = val.y;
      As[k + 2][n] = val.z;
      As[k + 3][n] = val.w;
    }
    // stage B tile (32 k x 64 r)
#pragma unroll
    for (int v = 0; v < 2; ++v) {
      int idx = tid + v * 256;
      int k = idx >> 4;             // 0..31
      int r = (idx & 15) << 2;      // 0,4,...,60
      *reinterpret_cast<float4*>(&Bs[k][r]) =
          *reinterpret_cast<const float4*>(&Wh[(size_t)(k0 + k) * RR + r]);
    }
    __syncthreads();

#pragma unroll
    for (int k = 0; k < 32; ++k) {
      const float4 a = *reinterpret_cast<const float4*>(&As[k][ty << 2]);
      const float4 b = *reinterpret_cast<const float4*>(&Bs[k][tx << 2]);
      acc[0][0] += a.x * b.x; acc[0][1] += a.x * b.y; acc[0][2] += a.x * b.z; acc[0][3] += a.x * b.w;
      acc[1][0] += a.y * b.x; acc[1][1] += a.y * b.y; acc[1][2] += a.y * b.z; acc[1][3] += a.y * b.w;
      acc[2][0] += a.z * b.x; acc[2][1] += a.z * b.y; acc[2][2] += a.z * b.z; acc[2][3] += a.z * b.w;
      acc[3][0] += a.w * b.x; acc[3][1] += a.w * b.y; acc[3][2] += a.w * b.z; acc[3][3] += a.w * b.w;
    }
    __syncthreads();
  }

#pragma unroll
  for (int i2 = 0; i2 < 4; ++i2) {
    float4 v = make_float4(acc[i2][0], acc[i2][1], acc[i2][2], acc[i2][3]);
    *reinterpret_cast<float4*>(
        &hidden[((size_t)h * NN + row0 + (ty << 2) + i2) * RR + (tx << 2)]) = v;
  }
}

// ---------------------------------------------------------------------------
// K2: a_src[h][n] = hidden[h][n][:] . sa[h][0:R]; a_dst similarly with sa[h][R:2R]
// ---------------------------------------------------------------------------
__global__ __launch_bounds__(256) void k_src_dst(
    const float* __restrict__ hidden,
    const float* __restrict__ sa,
    float* __restrict__ a_src,
    float* __restrict__ a_dst)
{
  const int idx = blockIdx.x * 256 + threadIdx.x;  // 0 .. H*N
  const int h = idx >> 12;                         // N = 4096
  const float4* hp = reinterpret_cast<const float4*>(hidden + (size_t)idx * RR);
  const float4* ws = reinterpret_cast<const float4*>(sa + (size_t)h * 2 * RR);
  const float4* wd = reinterpret_cast<const float4*>(sa + (size_t)h * 2 * RR + RR);
  float s = 0.f, d = 0.f;
#pragma unroll
  for (int v = 0; v < 16; ++v) {
    const float4 hv = hp[v];
    const float4 sv = ws[v];
    const float4 dv = wd[v];
    s += hv.x * sv.x + hv.y * sv.y + hv.z * sv.z + hv.w * sv.w;
    d += hv.x * dv.x + hv.y * dv.y + hv.z * dv.z + hv.w * dv.w;
  }
  a_src[idx] = s;
  a_dst[idx] = d;
}

// ---------------------------------------------------------------------------
// K3: one block per destination row i.
//  phase 1: deterministic ordered compaction of neighbor column indices
//  phase 2: gather bias at neighbors, per-head scores + LeakyReLU
//  phase 3: per-head softmax (8 groups of 32 lanes)
//  phase 4: out[i, h*R+r] = sum_t att[h][t] * hidden[h][cols[t]][r]
// ---------------------------------------------------------------------------
__global__ __launch_bounds__(256) void k_gat_row(
    const float* __restrict__ adj,
    const float* __restrict__ bias,
    const float* __restrict__ a_src,
    const float* __restrict__ a_dst,
    const float* __restrict__ hidden,
    float* __restrict__ out)
{
  const int i = blockIdx.x;
  const int tid = threadIdx.x;
  const int lane = tid & 63;
  const int wave = tid >> 6;

  __shared__ int cols[CAP];
  __shared__ float bvals[CAP];
  __shared__ float att[HH][CAP];
  __shared__ int wsum[4];

  const float* arow = adj + (size_t)i * NN;
  const float* brow = bias + (size_t)i * NN;

  // ---- phase 1: ordered compaction (deterministic: cols ascending) ----
  int total = 0;
  for (int j0 = 0; j0 < NN; j0 += 256) {
    const int j = j0 + tid;
    const float a = arow[j];
    const bool pred = (a != 0.0f);
    const unsigned long long m = __ballot(pred);
    if (lane == 0) wsum[wave] = __popcll(m);
    __syncthreads();
    int off = total;
    for (int w = 0; w < wave; ++w) off += wsum[w];
    if (pred) {
      const int p = off + __popcll(m & ((1ull << lane) - 1ull));
      if (p < CAP) cols[p] = j;
    }
    total += wsum[0] + wsum[1] + wsum[2] + wsum[3];
    __syncthreads();
  }
  const int count = total < CAP ? total : CAP;

  // ---- phase 2: gather bias, compute scores ----
  for (int t = tid; t < count; t += 256) bvals[t] = brow[cols[t]];
  __syncthreads();

#pragma unroll
  for (int h = 0; h < HH; ++h) {
    const float asrc = a_src[(size_t)h * NN + i];
    for (int t = tid; t < count; t += 256) {
      float s = asrc + a_dst[(size_t)h * NN + cols[t]] + 0.01f * bvals[t];
      s = (s >= 0.f) ? s : 0.2f * s;  // LeakyReLU(0.2)
      att[h][t] = s;
    }
  }
  __syncthreads();

  // ---- phase 3: per-head softmax; group g (32 lanes) owns head g ----
  {
    const int g = tid >> 5;
    const int l = tid & 31;
    float m = -3.0e38f;
    for (int t = l; t < count; t += 32) m = fmaxf(m, att[g][t]);
#pragma unroll
    for (int o = 16; o >= 1; o >>= 1) m = fmaxf(m, __shfl_xor(m, o));
    float s = 0.f;
    for (int t = l; t < count; t += 32) {
      const float e = expf(att[g][t] - m);
      att[g][t] = e;
      s += e;
    }
#pragma unroll
    for (int o = 16; o >= 1; o >>= 1) s += __shfl_xor(s, o);
    const float inv = 1.0f / s;
    for (int t = l; t < count; t += 32) att[g][t] *= inv;
  }
  __syncthreads();

  // ---- phase 4: sparse aggregation ----
#pragma unroll
  for (int oo = 0; oo < 2; ++oo) {
    const int o = tid + oo * 256;   // 0..511
    const int h = o >> 6;
    const int r = o & 63;
    const float* hb = hidden + ((size_t)h * NN) * RR + r;
    float acc = 0.f;
    for (int t = 0; t < count; ++t) {
      acc += att[h][t] * hb[(size_t)cols[t] * RR];
    }
    out[(size_t)i * (HH * RR) + o] = acc;
  }
}

extern "C" void kernel_launch(void* const* d_in, const int* in_sizes, int n_in,
                              void* d_out, int out_size, void* d_ws, size_t ws_size,
                              hipStream_t stream) {
  const float* X    = (const float*)d_in[0];   // [N,F]
  const float* adj  = (const float*)d_in[1];   // [N,N]
  const float* W    = (const float*)d_in[2];   // [H,F,R]
  const float* sa   = (const float*)d_in[3];   // [H,2R]
  const float* bias = (const float*)d_in[4];   // [N,N]
  float* out = (float*)d_out;                  // [N, H*R]

  float* hidden = (float*)d_ws;                        // 8 MB
  float* a_src  = hidden + (size_t)HH * NN * RR;       // 128 KB
  float* a_dst  = a_src + (size_t)HH * NN;             // 128 KB

  k_gemm_hidden<<<dim3(NN / 64, HH), 256, 0, stream>>>(X, W, hidden);
  k_src_dst<<<dim3((HH * NN) / 256), 256, 0, stream>>>(hidden, sa, a_src, a_dst);
  k_gat_row<<<dim3(NN), 256, 0, stream>>>(adj, bias, a_src, a_dst, hidden, out);
}

// Round 2
// 95.137 us; speedup vs baseline: 1.1878x; 1.1878x over previous
//
#include <hip/hip_runtime.h>
#include <hip/hip_bf16.h>

#define NN 4096
#define FF 512
#define RR 64
#define HH 8
#define CAP 256

// ---------------------------------------------------------------------------
// K1: hidden[h][n][r] = sum_f X[n][f] * W[h][f][r]
// block = 256 threads, computes 64 rows x 64 cols (full R) for one head.
// ---------------------------------------------------------------------------
__global__ __launch_bounds__(256) void k_gemm_hidden(
    const float* __restrict__ X,
    const float* __restrict__ W,
    float* __restrict__ hidden)
{
  const int h = blockIdx.y;
  const int row0 = blockIdx.x * 64;
  __shared__ float As[32][68];  // [k][n], padded
  __shared__ float Bs[32][64];  // [k][r]
  const int tid = threadIdx.x;
  const int tx = tid & 15;   // col group (4 cols)
  const int ty = tid >> 4;   // row group (4 rows)
  float acc[4][4] = {{0.f, 0.f, 0.f, 0.f}, {0.f, 0.f, 0.f, 0.f},
                     {0.f, 0.f, 0.f, 0.f}, {0.f, 0.f, 0.f, 0.f}};
  const float* Wh = W + (size_t)h * FF * RR;

  for (int k0 = 0; k0 < FF; k0 += 32) {
#pragma unroll
    for (int v = 0; v < 2; ++v) {
      int idx = tid + v * 256;
      int n = idx >> 3;
      int k = (idx & 7) << 2;
      const float4 val =
          *reinterpret_cast<const float4*>(&X[(size_t)(row0 + n) * FF + k0 + k]);
      As[k + 0][n] = val.x;
      As[k + 1][n] = val.y;
      As[k + 2][n] = val.z;
      As[k + 3][n] = val.w;
    }
#pragma unroll
    for (int v = 0; v < 2; ++v) {
      int idx = tid + v * 256;
      int k = idx >> 4;
      int r = (idx & 15) << 2;
      *reinterpret_cast<float4*>(&Bs[k][r]) =
          *reinterpret_cast<const float4*>(&Wh[(size_t)(k0 + k) * RR + r]);
    }
    __syncthreads();

#pragma unroll
    for (int k = 0; k < 32; ++k) {
      const float4 a = *reinterpret_cast<const float4*>(&As[k][ty << 2]);
      const float4 b = *reinterpret_cast<const float4*>(&Bs[k][tx << 2]);
      acc[0][0] += a.x * b.x; acc[0][1] += a.x * b.y; acc[0][2] += a.x * b.z; acc[0][3] += a.x * b.w;
      acc[1][0] += a.y * b.x; acc[1][1] += a.y * b.y; acc[1][2] += a.y * b.z; acc[1][3] += a.y * b.w;
      acc[2][0] += a.z * b.x; acc[2][1] += a.z * b.y; acc[2][2] += a.z * b.z; acc[2][3] += a.z * b.w;
      acc[3][0] += a.w * b.x; acc[3][1] += a.w * b.y; acc[3][2] += a.w * b.z; acc[3][3] += a.w * b.w;
    }
    __syncthreads();
  }

#pragma unroll
  for (int i2 = 0; i2 < 4; ++i2) {
    float4 v = make_float4(acc[i2][0], acc[i2][1], acc[i2][2], acc[i2][3]);
    *reinterpret_cast<float4*>(
        &hidden[((size_t)h * NN + row0 + (ty << 2) + i2) * RR + (tx << 2)]) = v;
  }
}

// ---------------------------------------------------------------------------
// K2: a_src[h][n] (kept [H][N]) and a_dstT[n][h] (transposed for phase-2 gathers)
// ---------------------------------------------------------------------------
__global__ __launch_bounds__(256) void k_src_dst(
    const float* __restrict__ hidden,
    const float* __restrict__ sa,
    float* __restrict__ a_src,
    float* __restrict__ a_dstT)
{
  const int idx = blockIdx.x * 256 + threadIdx.x;  // 0 .. H*N
  const int h = idx >> 12;                         // N = 4096
  const int n = idx & (NN - 1);
  const float4* hp = reinterpret_cast<const float4*>(hidden + (size_t)idx * RR);
  const float4* ws = reinterpret_cast<const float4*>(sa + (size_t)h * 2 * RR);
  const float4* wd = reinterpret_cast<const float4*>(sa + (size_t)h * 2 * RR + RR);
  float s = 0.f, d = 0.f;
#pragma unroll
  for (int v = 0; v < 16; ++v) {
    const float4 hv = hp[v];
    const float4 sv = ws[v];
    const float4 dv = wd[v];
    s += hv.x * sv.x + hv.y * sv.y + hv.z * sv.z + hv.w * sv.w;
    d += hv.x * dv.x + hv.y * dv.y + hv.z * dv.z + hv.w * dv.w;
  }
  a_src[idx] = s;
  a_dstT[(size_t)n * HH + h] = d;
}

// ---------------------------------------------------------------------------
// K3: one block (256 thr) per destination row i.
//  phase 1: prefetch whole adjacency row (4x float4/thread, all in flight),
//           16-bit predicate mask, ONE block prefix-sum, 2 barriers.
//  phase 2: per-neighbor: bias gather + a_dstT float4 x2 -> 8 head scores.
//  phase 3: per-head softmax (8 groups of 32 lanes).
//  phase 4: sparse aggregation.
// ---------------------------------------------------------------------------
__global__ __launch_bounds__(256) void k_gat_row(
    const float* __restrict__ adj,
    const float* __restrict__ bias,
    const float* __restrict__ a_src,
    const float* __restrict__ a_dstT,
    const float* __restrict__ hidden,
    float* __restrict__ out)
{
  const int i = blockIdx.x;
  const int tid = threadIdx.x;
  const int lane = tid & 63;
  const int wave = tid >> 6;

  __shared__ int cols[CAP];
  __shared__ float att[HH][CAP];
  __shared__ int wsum[4];

  const float* arow = adj + (size_t)i * NN;
  const float* brow = bias + (size_t)i * NN;

  // ---- phase 1: prefetch + compaction with a single prefix-sum ----
  float4 v0 = *reinterpret_cast<const float4*>(&arow[0 * 1024 + (tid << 2)]);
  float4 v1 = *reinterpret_cast<const float4*>(&arow[1 * 1024 + (tid << 2)]);
  float4 v2 = *reinterpret_cast<const float4*>(&arow[2 * 1024 + (tid << 2)]);
  float4 v3 = *reinterpret_cast<const float4*>(&arow[3 * 1024 + (tid << 2)]);

  int pm = 0;
  if (v0.x != 0.f) pm |= 1 << 0;
  if (v0.y != 0.f) pm |= 1 << 1;
  if (v0.z != 0.f) pm |= 1 << 2;
  if (v0.w != 0.f) pm |= 1 << 3;
  if (v1.x != 0.f) pm |= 1 << 4;
  if (v1.y != 0.f) pm |= 1 << 5;
  if (v1.z != 0.f) pm |= 1 << 6;
  if (v1.w != 0.f) pm |= 1 << 7;
  if (v2.x != 0.f) pm |= 1 << 8;
  if (v2.y != 0.f) pm |= 1 << 9;
  if (v2.z != 0.f) pm |= 1 << 10;
  if (v2.w != 0.f) pm |= 1 << 11;
  if (v3.x != 0.f) pm |= 1 << 12;
  if (v3.y != 0.f) pm |= 1 << 13;
  if (v3.z != 0.f) pm |= 1 << 14;
  if (v3.w != 0.f) pm |= 1 << 15;
  const int cnt = __popc(pm);

  // wave-level inclusive prefix sum of cnt
  int pfx = cnt;
#pragma unroll
  for (int off = 1; off < 64; off <<= 1) {
    const int o = __shfl_up(pfx, off);
    if (lane >= off) pfx += o;
  }
  if (lane == 63) wsum[wave] = pfx;
  __syncthreads();

  int base = 0;
#pragma unroll
  for (int w = 0; w < 4; ++w)
    if (w < wave) base += wsum[w];
  const int total = wsum[0] + wsum[1] + wsum[2] + wsum[3];
  const int count = total < CAP ? total : CAP;

  int pos = base + pfx - cnt;
#pragma unroll
  for (int c = 0; c < 4; ++c) {
#pragma unroll
    for (int k = 0; k < 4; ++k) {
      if (pm & (1 << (c * 4 + k))) {
        if (pos < CAP) cols[pos] = c * 1024 + (tid << 2) + k;
        ++pos;
      }
    }
  }
  __syncthreads();

  // ---- phase 2: scores for all 8 heads in one pass ----
  float asrc[HH];
#pragma unroll
  for (int h = 0; h < HH; ++h) asrc[h] = a_src[(size_t)h * NN + i];

  for (int t = tid; t < count; t += 256) {
    const int c = cols[t];
    const float b = 0.01f * brow[c];
    const float4 d0 = *reinterpret_cast<const float4*>(&a_dstT[(size_t)c * HH]);
    const float4 d1 = *reinterpret_cast<const float4*>(&a_dstT[(size_t)c * HH + 4]);
    float s;
    s = asrc[0] + d0.x + b; att[0][t] = (s >= 0.f) ? s : 0.2f * s;
    s = asrc[1] + d0.y + b; att[1][t] = (s >= 0.f) ? s : 0.2f * s;
    s = asrc[2] + d0.z + b; att[2][t] = (s >= 0.f) ? s : 0.2f * s;
    s = asrc[3] + d0.w + b; att[3][t] = (s >= 0.f) ? s : 0.2f * s;
    s = asrc[4] + d1.x + b; att[4][t] = (s >= 0.f) ? s : 0.2f * s;
    s = asrc[5] + d1.y + b; att[5][t] = (s >= 0.f) ? s : 0.2f * s;
    s = asrc[6] + d1.z + b; att[6][t] = (s >= 0.f) ? s : 0.2f * s;
    s = asrc[7] + d1.w + b; att[7][t] = (s >= 0.f) ? s : 0.2f * s;
  }
  __syncthreads();

  // ---- phase 3: per-head softmax; group g (32 lanes) owns head g ----
  {
    const int g = tid >> 5;
    const int l = tid & 31;
    float m = -3.0e38f;
    for (int t = l; t < count; t += 32) m = fmaxf(m, att[g][t]);
#pragma unroll
    for (int o = 16; o >= 1; o >>= 1) m = fmaxf(m, __shfl_xor(m, o));
    float ssum = 0.f;
    for (int t = l; t < count; t += 32) {
      const float e = expf(att[g][t] - m);
      att[g][t] = e;
      ssum += e;
    }
#pragma unroll
    for (int o = 16; o >= 1; o >>= 1) ssum += __shfl_xor(ssum, o);
    const float inv = 1.0f / ssum;
    for (int t = l; t < count; t += 32) att[g][t] *= inv;
  }
  __syncthreads();

  // ---- phase 4: sparse aggregation ----
#pragma unroll
  for (int oo = 0; oo < 2; ++oo) {
    const int o = tid + oo * 256;   // 0..511
    const int h = o >> 6;
    const int r = o & 63;
    const float* hb = hidden + ((size_t)h * NN) * RR + r;
    float acc0 = 0.f, acc1 = 0.f;
    int t = 0;
    for (; t + 1 < count; t += 2) {
      acc0 += att[h][t] * hb[(size_t)cols[t] * RR];
      acc1 += att[h][t + 1] * hb[(size_t)cols[t + 1] * RR];
    }
    if (t < count) acc0 += att[h][t] * hb[(size_t)cols[t] * RR];
    out[(size_t)i * (HH * RR) + o] = acc0 + acc1;
  }
}

extern "C" void kernel_launch(void* const* d_in, const int* in_sizes, int n_in,
                              void* d_out, int out_size, void* d_ws, size_t ws_size,
                              hipStream_t stream) {
  const float* X    = (const float*)d_in[0];   // [N,F]
  const float* adj  = (const float*)d_in[1];   // [N,N]
  const float* W    = (const float*)d_in[2];   // [H,F,R]
  const float* sa   = (const float*)d_in[3];   // [H,2R]
  const float* bias = (const float*)d_in[4];   // [N,N]
  float* out = (float*)d_out;                  // [N, H*R]

  float* hidden = (float*)d_ws;                        // 8 MB
  float* a_src  = hidden + (size_t)HH * NN * RR;       // 128 KB
  float* a_dstT = a_src + (size_t)HH * NN;             // 128 KB

  k_gemm_hidden<<<dim3(NN / 64, HH), 256, 0, stream>>>(X, W, hidden);
  k_src_dst<<<dim3((HH * NN) / 256), 256, 0, stream>>>(hidden, sa, a_src, a_dstT);
  k_gat_row<<<dim3(NN), 256, 0, stream>>>(adj, bias, a_src, a_dstT, hidden, out);
}

// Round 3
// 84.237 us; speedup vs baseline: 1.3415x; 1.1294x over previous
//
#include <hip/hip_runtime.h>
#include <hip/hip_bf16.h>

#define NN 4096
#define FF 512
#define RR 64
#define HH 8
#define CAP 128          // max degree ~76 (binom(4096,0.01)+self); 128 is >8 sigma
#define ATT_STRIDE 132   // 128 + 4 pad: de-conflicts stride-8 softmax access

// ---------------------------------------------------------------------------
// K1: hiddenT[n][h*64+r] = sum_f X[n][f] * W[h][f][r]   (note: [n][h][r] layout)
// block = 256 threads, computes 64 rows x 64 cols (full R) for one head.
// ---------------------------------------------------------------------------
__global__ __launch_bounds__(256) void k_gemm_hidden(
    const float* __restrict__ X,
    const float* __restrict__ W,
    float* __restrict__ hiddenT)
{
  const int h = blockIdx.y;
  const int row0 = blockIdx.x * 64;
  __shared__ float As[32][68];  // [k][n], padded
  __shared__ float Bs[32][64];  // [k][r]
  const int tid = threadIdx.x;
  const int tx = tid & 15;   // col group (4 cols)
  const int ty = tid >> 4;   // row group (4 rows)
  float acc[4][4] = {{0.f, 0.f, 0.f, 0.f}, {0.f, 0.f, 0.f, 0.f},
                     {0.f, 0.f, 0.f, 0.f}, {0.f, 0.f, 0.f, 0.f}};
  const float* Wh = W + (size_t)h * FF * RR;

  for (int k0 = 0; k0 < FF; k0 += 32) {
#pragma unroll
    for (int v = 0; v < 2; ++v) {
      int idx = tid + v * 256;
      int n = idx >> 3;
      int k = (idx & 7) << 2;
      const float4 val =
          *reinterpret_cast<const float4*>(&X[(size_t)(row0 + n) * FF + k0 + k]);
      As[k + 0][n] = val.x;
      As[k + 1][n] = val.y;
      As[k + 2][n] = val.z;
      As[k + 3][n] = val.w;
    }
#pragma unroll
    for (int v = 0; v < 2; ++v) {
      int idx = tid + v * 256;
      int k = idx >> 4;
      int r = (idx & 15) << 2;
      *reinterpret_cast<float4*>(&Bs[k][r]) =
          *reinterpret_cast<const float4*>(&Wh[(size_t)(k0 + k) * RR + r]);
    }
    __syncthreads();

#pragma unroll
    for (int k = 0; k < 32; ++k) {
      const float4 a = *reinterpret_cast<const float4*>(&As[k][ty << 2]);
      const float4 b = *reinterpret_cast<const float4*>(&Bs[k][tx << 2]);
      acc[0][0] += a.x * b.x; acc[0][1] += a.x * b.y; acc[0][2] += a.x * b.z; acc[0][3] += a.x * b.w;
      acc[1][0] += a.y * b.x; acc[1][1] += a.y * b.y; acc[1][2] += a.y * b.z; acc[1][3] += a.y * b.w;
      acc[2][0] += a.z * b.x; acc[2][1] += a.z * b.y; acc[2][2] += a.z * b.z; acc[2][3] += a.z * b.w;
      acc[3][0] += a.w * b.x; acc[3][1] += a.w * b.y; acc[3][2] += a.w * b.z; acc[3][3] += a.w * b.w;
    }
    __syncthreads();
  }

#pragma unroll
  for (int i2 = 0; i2 < 4; ++i2) {
    float4 v = make_float4(acc[i2][0], acc[i2][1], acc[i2][2], acc[i2][3]);
    *reinterpret_cast<float4*>(
        &hiddenT[(size_t)(row0 + (ty << 2) + i2) * (HH * RR) + h * RR + (tx << 2)]) = v;
  }
}

// ---------------------------------------------------------------------------
// K2: a_src[h][n], a_dstT[n][h] from hiddenT[n][h*64+r].
// thread -> (h = idx&7, n = idx>>3) so 8 consecutive threads cover one node's
// contiguous 2KB [h][r] stripe.
// ---------------------------------------------------------------------------
__global__ __launch_bounds__(256) void k_src_dst(
    const float* __restrict__ hiddenT,
    const float* __restrict__ sa,
    float* __restrict__ a_src,
    float* __restrict__ a_dstT)
{
  const int idx = blockIdx.x * 256 + threadIdx.x;  // 0 .. H*N
  const int h = idx & 7;
  const int n = idx >> 3;
  const float4* hp = reinterpret_cast<const float4*>(hiddenT + (size_t)n * (HH * RR) + h * RR);
  const float4* ws = reinterpret_cast<const float4*>(sa + (size_t)h * 2 * RR);
  const float4* wd = reinterpret_cast<const float4*>(sa + (size_t)h * 2 * RR + RR);
  float s = 0.f, d = 0.f;
#pragma unroll
  for (int v = 0; v < 16; ++v) {
    const float4 hv = hp[v];
    const float4 sv = ws[v];
    const float4 dv = wd[v];
    s += hv.x * sv.x + hv.y * sv.y + hv.z * sv.z + hv.w * sv.w;
    d += hv.x * dv.x + hv.y * dv.y + hv.z * dv.z + hv.w * dv.w;
  }
  a_src[(size_t)h * NN + n] = s;
  a_dstT[(size_t)n * HH + h] = d;
}

__device__ __forceinline__ unsigned nib4(const float4 v) {
  unsigned m = 0;
  if (v.x != 0.f) m |= 1u;
  if (v.y != 0.f) m |= 2u;
  if (v.z != 0.f) m |= 4u;
  if (v.w != 0.f) m |= 8u;
  return m;
}

// ---------------------------------------------------------------------------
// K3: ONE WAVE per destination row; 4 rows per 256-thread block; grid = 1024
// (4 blocks/CU -> every wave on the chip resident simultaneously).
// ---------------------------------------------------------------------------
__global__ __launch_bounds__(256) void k_gat_row(
    const float* __restrict__ adj,
    const float* __restrict__ bias,
    const float* __restrict__ a_src,
    const float* __restrict__ a_dstT,
    const float* __restrict__ hiddenT,
    float* __restrict__ out)
{
  const int tid = threadIdx.x;
  const int lane = tid & 63;
  const int wave = tid >> 6;
  const int row = blockIdx.x * 4 + wave;

  __shared__ __align__(16) float att[4][HH * ATT_STRIDE];  // 4224 B per wave
  __shared__ __align__(16) int colsS[4][CAP];              // 512 B per wave
  float* attW = att[wave];
  int* colsW = colsS[wave];

  const float* arow = adj + (size_t)row * NN;
  const float* brow = bias + (size_t)row * NN;

  // hoist per-row src scores (wave-uniform -> scalar loads), hides latency
  float asrc[HH];
#pragma unroll
  for (int h = 0; h < HH; ++h) asrc[h] = a_src[(size_t)h * NN + row];

  // ---- phase 1: two batches of 8 float4 loads (8 lines in flight/lane) ----
  unsigned pm0 = 0, pm1 = 0;
  {
    float4 buf[8];
#pragma unroll
    for (int c = 0; c < 8; ++c)
      buf[c] = *reinterpret_cast<const float4*>(&arow[c * 256 + (lane << 2)]);
#pragma unroll
    for (int c = 0; c < 8; ++c) pm0 |= nib4(buf[c]) << (4 * c);
#pragma unroll
    for (int c = 0; c < 8; ++c)
      buf[c] = *reinterpret_cast<const float4*>(&arow[(c + 8) * 256 + (lane << 2)]);
#pragma unroll
    for (int c = 0; c < 8; ++c) pm1 |= nib4(buf[c]) << (4 * c);
  }
  const int cnt = __popc(pm0) + __popc(pm1);

  // wave-inclusive prefix sum of cnt
  int pfx = cnt;
#pragma unroll
  for (int off = 1; off < 64; off <<= 1) {
    const int o = __shfl_up(pfx, off);
    if (lane >= off) pfx += o;
  }
  const int total = __shfl(pfx, 63);
  const int count = total < CAP ? total : CAP;

  // write this lane's neighbor columns (deterministic lane-major order)
  {
    int pos = pfx - cnt;
    unsigned m = pm0;
    while (m) {
      const int b = __builtin_ctz(m);
      m &= m - 1;
      if (pos < CAP) colsW[pos] = ((b >> 2) << 8) + (lane << 2) + (b & 3);
      ++pos;
    }
    m = pm1;
    while (m) {
      const int b = __builtin_ctz(m);
      m &= m - 1;
      if (pos < CAP) colsW[pos] = 2048 + ((b >> 2) << 8) + (lane << 2) + (b & 3);
      ++pos;
    }
  }
  __syncthreads();

  // ---- phase 2: scores for all 8 heads (<=2 iterations) ----
  for (int t = lane; t < count; t += 64) {
    const int c = colsW[t];
    const float b = 0.01f * brow[c];
    const float4 d0 = *reinterpret_cast<const float4*>(&a_dstT[(size_t)c * HH]);
    const float4 d1 = *reinterpret_cast<const float4*>(&a_dstT[(size_t)c * HH + 4]);
    float s;
    s = asrc[0] + d0.x + b; attW[0 * ATT_STRIDE + t] = (s >= 0.f) ? s : 0.2f * s;
    s = asrc[1] + d0.y + b; attW[1 * ATT_STRIDE + t] = (s >= 0.f) ? s : 0.2f * s;
    s = asrc[2] + d0.z + b; attW[2 * ATT_STRIDE + t] = (s >= 0.f) ? s : 0.2f * s;
    s = asrc[3] + d0.w + b; attW[3 * ATT_STRIDE + t] = (s >= 0.f) ? s : 0.2f * s;
    s = asrc[4] + d1.x + b; attW[4 * ATT_STRIDE + t] = (s >= 0.f) ? s : 0.2f * s;
    s = asrc[5] + d1.y + b; attW[5 * ATT_STRIDE + t] = (s >= 0.f) ? s : 0.2f * s;
    s = asrc[6] + d1.z + b; attW[6 * ATT_STRIDE + t] = (s >= 0.f) ? s : 0.2f * s;
    s = asrc[7] + d1.w + b; attW[7 * ATT_STRIDE + t] = (s >= 0.f) ? s : 0.2f * s;
  }
  __syncthreads();

  // ---- phase 3: softmax; 8-lane group g owns head g ----
  {
    const int g = lane >> 3;
    const int l8 = lane & 7;
    float* arow_h = attW + g * ATT_STRIDE;
    float m = -3.0e38f;
    for (int t = l8; t < count; t += 8) m = fmaxf(m, arow_h[t]);
#pragma unroll
    for (int o = 4; o >= 1; o >>= 1) m = fmaxf(m, __shfl_xor(m, o));
    float ssum = 0.f;
    for (int t = l8; t < count; t += 8) {
      const float e = expf(arow_h[t] - m);
      arow_h[t] = e;
      ssum += e;
    }
#pragma unroll
    for (int o = 4; o >= 1; o >>= 1) ssum += __shfl_xor(ssum, o);
    const float inv = 1.0f / ssum;
    for (int t = l8; t < count; t += 8) arow_h[t] *= inv;
  }
  __syncthreads();

  // ---- phase 4: aggregation. lane owns outputs [h*64 + rbase .. +7],
  // h = lane>>3. Per neighbor: one contiguous 2KB wave read of hiddenT[c]. ----
  {
    const int h = lane >> 3;
    const int rbase = (lane & 7) << 3;
    const float* attrow = attW + h * ATT_STRIDE;
    const float* hb = hiddenT + (size_t)h * RR + rbase;
    float4 acc0 = make_float4(0.f, 0.f, 0.f, 0.f);
    float4 acc1 = make_float4(0.f, 0.f, 0.f, 0.f);
    int t = 0;
    for (; t + 4 <= count; t += 4) {
      const int4 c4 = *reinterpret_cast<const int4*>(&colsW[t]);
      const float4 a4 = *reinterpret_cast<const float4*>(&attrow[t]);
#pragma unroll
      for (int j = 0; j < 4; ++j) {
        const int c = (j == 0) ? c4.x : (j == 1) ? c4.y : (j == 2) ? c4.z : c4.w;
        const float a = (j == 0) ? a4.x : (j == 1) ? a4.y : (j == 2) ? a4.z : a4.w;
        const float4* hp = reinterpret_cast<const float4*>(hb + (size_t)c * (HH * RR));
        const float4 v0 = hp[0];
        const float4 v1 = hp[1];
        acc0.x += a * v0.x; acc0.y += a * v0.y; acc0.z += a * v0.z; acc0.w += a * v0.w;
        acc1.x += a * v1.x; acc1.y += a * v1.y; acc1.z += a * v1.z; acc1.w += a * v1.w;
      }
    }
    for (; t < count; ++t) {
      const int c = colsW[t];
      const float a = attrow[t];
      const float4* hp = reinterpret_cast<const float4*>(hb + (size_t)c * (HH * RR));
      const float4 v0 = hp[0];
      const float4 v1 = hp[1];
      acc0.x += a * v0.x; acc0.y += a * v0.y; acc0.z += a * v0.z; acc0.w += a * v0.w;
      acc1.x += a * v1.x; acc1.y += a * v1.y; acc1.z += a * v1.z; acc1.w += a * v1.w;
    }
    float* op = out + (size_t)row * (HH * RR) + h * RR + rbase;
    *reinterpret_cast<float4*>(op) = acc0;
    *reinterpret_cast<float4*>(op + 4) = acc1;
  }
}

extern "C" void kernel_launch(void* const* d_in, const int* in_sizes, int n_in,
                              void* d_out, int out_size, void* d_ws, size_t ws_size,
                              hipStream_t stream) {
  const float* X    = (const float*)d_in[0];   // [N,F]
  const float* adj  = (const float*)d_in[1];   // [N,N]
  const float* W    = (const float*)d_in[2];   // [H,F,R]
  const float* sa   = (const float*)d_in[3];   // [H,2R]
  const float* bias = (const float*)d_in[4];   // [N,N]
  float* out = (float*)d_out;                  // [N, H*R]

  float* hiddenT = (float*)d_ws;                        // [N][H*R], 8 MB
  float* a_src   = hiddenT + (size_t)NN * HH * RR;      // [H][N], 128 KB
  float* a_dstT  = a_src + (size_t)HH * NN;             // [N][H], 128 KB

  k_gemm_hidden<<<dim3(NN / 64, HH), 256, 0, stream>>>(X, W, hiddenT);
  k_src_dst<<<dim3((HH * NN) / 256), 256, 0, stream>>>(hiddenT, sa, a_src, a_dstT);
  k_gat_row<<<dim3(NN / 4), 256, 0, stream>>>(adj, bias, a_src, a_dstT, hiddenT, out);
}

// Round 4
// 67.322 us; speedup vs baseline: 1.6786x; 1.2513x over previous
//
#include <hip/hip_runtime.h>
#include <hip/hip_bf16.h>

#define NN 4096
#define FF 512
#define RR 64
#define HH 8
#define CAP 128          // max degree ~76; 128 is huge margin
#define ATT_STRIDE 132   // 128 + 4 pad

__device__ __forceinline__ unsigned short f2bf(float f) {
  __hip_bfloat16 h = __float2bfloat16(f);   // RNE
  return *reinterpret_cast<unsigned short*>(&h);
}
__device__ __forceinline__ float bf2f(unsigned short u) {
  union { unsigned u32; float f; } cv;
  cv.u32 = ((unsigned)u) << 16;
  return cv.f;
}

// ---------------------------------------------------------------------------
// K1: hiddenT[n][h*64+r] (bf16) = sum_f X[n][f] * W[h][f][r]
//     + fused epilogue: a_src[h][n], a_dstT[n][h] (fp32, from fp32 acc)
// block = 256 threads -> 64 rows x 64 cols (full R) for one head.
// ---------------------------------------------------------------------------
__global__ __launch_bounds__(256) void k_gemm_hidden(
    const float* __restrict__ X,
    const float* __restrict__ W,
    const float* __restrict__ sa,
    unsigned short* __restrict__ hiddenT,
    float* __restrict__ a_src,
    float* __restrict__ a_dstT)
{
  const int h = blockIdx.y;
  const int row0 = blockIdx.x * 64;
  __shared__ float As[32][68];  // [k][n], padded; reused by epilogue
  __shared__ float Bs[32][64];  // [k][r]
  const int tid = threadIdx.x;
  const int tx = tid & 15;   // col group (4 cols)
  const int ty = tid >> 4;   // row group (4 rows)
  float acc[4][4] = {{0.f, 0.f, 0.f, 0.f}, {0.f, 0.f, 0.f, 0.f},
                     {0.f, 0.f, 0.f, 0.f}, {0.f, 0.f, 0.f, 0.f}};
  const float* Wh = W + (size_t)h * FF * RR;

  for (int k0 = 0; k0 < FF; k0 += 32) {
#pragma unroll
    for (int v = 0; v < 2; ++v) {
      int idx = tid + v * 256;
      int n = idx >> 3;
      int k = (idx & 7) << 2;
      const float4 val =
          *reinterpret_cast<const float4*>(&X[(size_t)(row0 + n) * FF + k0 + k]);
      As[k + 0][n] = val.x;
      As[k + 1][n] = val.y;
      As[k + 2][n] = val.z;
      As[k + 3][n] = val.w;
    }
#pragma unroll
    for (int v = 0; v < 2; ++v) {
      int idx = tid + v * 256;
      int k = idx >> 4;
      int r = (idx & 15) << 2;
      *reinterpret_cast<float4*>(&Bs[k][r]) =
          *reinterpret_cast<const float4*>(&Wh[(size_t)(k0 + k) * RR + r]);
    }
    __syncthreads();

#pragma unroll
    for (int k = 0; k < 32; ++k) {
      const float4 a = *reinterpret_cast<const float4*>(&As[k][ty << 2]);
      const float4 b = *reinterpret_cast<const float4*>(&Bs[k][tx << 2]);
      acc[0][0] += a.x * b.x; acc[0][1] += a.x * b.y; acc[0][2] += a.x * b.z; acc[0][3] += a.x * b.w;
      acc[1][0] += a.y * b.x; acc[1][1] += a.y * b.y; acc[1][2] += a.y * b.z; acc[1][3] += a.y * b.w;
      acc[2][0] += a.z * b.x; acc[2][1] += a.z * b.y; acc[2][2] += a.z * b.z; acc[2][3] += a.z * b.w;
      acc[3][0] += a.w * b.x; acc[3][1] += a.w * b.y; acc[3][2] += a.w * b.z; acc[3][3] += a.w * b.w;
    }
    __syncthreads();
  }

  // ---- write bf16 hiddenT ----
  const int col0 = tx << 2;
#pragma unroll
  for (int i2 = 0; i2 < 4; ++i2) {
    const int row = row0 + (ty << 2) + i2;
    ushort4 u;
    u.x = f2bf(acc[i2][0]); u.y = f2bf(acc[i2][1]);
    u.z = f2bf(acc[i2][2]); u.w = f2bf(acc[i2][3]);
    *reinterpret_cast<ushort4*>(&hiddenT[(size_t)row * (HH * RR) + h * RR + col0]) = u;
  }

  // ---- fused a_src / a_dst (fp32): block owns full R for this head ----
  float ssrc[4], sdst[4];
#pragma unroll
  for (int j = 0; j < 4; ++j) {
    ssrc[j] = sa[(size_t)h * 2 * RR + col0 + j];
    sdst[j] = sa[(size_t)h * 2 * RR + RR + col0 + j];
  }
  float* redS = &As[0][0];          // 1024 floats
  float* redD = &As[0][0] + 1024;   // 1024 floats (As has 2176)
#pragma unroll
  for (int i2 = 0; i2 < 4; ++i2) {
    float ps = acc[i2][0] * ssrc[0] + acc[i2][1] * ssrc[1] +
               acc[i2][2] * ssrc[2] + acc[i2][3] * ssrc[3];
    float pd = acc[i2][0] * sdst[0] + acc[i2][1] * sdst[1] +
               acc[i2][2] * sdst[2] + acc[i2][3] * sdst[3];
    redS[((ty << 2) + i2) * 16 + tx] = ps;
    redD[((ty << 2) + i2) * 16 + tx] = pd;
  }
  __syncthreads();
  if (tid < 64) {
    float s = 0.f, d = 0.f;
#pragma unroll
    for (int k = 0; k < 16; ++k) {
      s += redS[tid * 16 + k];
      d += redD[tid * 16 + k];
    }
    a_src[(size_t)h * NN + row0 + tid] = s;
    a_dstT[(size_t)(row0 + tid) * HH + h] = d;
  }
}

// ---------------------------------------------------------------------------
// K3: one block (256 thr, 4 waves) per row. Phase 4 splits the 512 outputs
// across the 4 waves (wave w owns [128w,128w+128)) -> 4x gather parallelism,
// grid 4096 -> ~100% occupancy target.
// ---------------------------------------------------------------------------
__global__ __launch_bounds__(256) void k_gat_row(
    const float* __restrict__ adj,
    const float* __restrict__ bias,
    const float* __restrict__ a_src,
    const float* __restrict__ a_dstT,
    const unsigned short* __restrict__ hiddenT,
    float* __restrict__ out)
{
  const int i = blockIdx.x;
  const int tid = threadIdx.x;
  const int lane = tid & 63;
  const int wave = tid >> 6;

  __shared__ __align__(16) float att[HH][ATT_STRIDE];
  __shared__ int cols[CAP];
  __shared__ int wsum[4];

  const float* arow = adj + (size_t)i * NN;
  const float* brow = bias + (size_t)i * NN;

  // ---- phase 1: 4 float4 loads/thread (all in flight), one block prefix ----
  float4 v0 = *reinterpret_cast<const float4*>(&arow[0 * 1024 + (tid << 2)]);
  float4 v1 = *reinterpret_cast<const float4*>(&arow[1 * 1024 + (tid << 2)]);
  float4 v2 = *reinterpret_cast<const float4*>(&arow[2 * 1024 + (tid << 2)]);
  float4 v3 = *reinterpret_cast<const float4*>(&arow[3 * 1024 + (tid << 2)]);

  int pm = 0;
  if (v0.x != 0.f) pm |= 1 << 0;
  if (v0.y != 0.f) pm |= 1 << 1;
  if (v0.z != 0.f) pm |= 1 << 2;
  if (v0.w != 0.f) pm |= 1 << 3;
  if (v1.x != 0.f) pm |= 1 << 4;
  if (v1.y != 0.f) pm |= 1 << 5;
  if (v1.z != 0.f) pm |= 1 << 6;
  if (v1.w != 0.f) pm |= 1 << 7;
  if (v2.x != 0.f) pm |= 1 << 8;
  if (v2.y != 0.f) pm |= 1 << 9;
  if (v2.z != 0.f) pm |= 1 << 10;
  if (v2.w != 0.f) pm |= 1 << 11;
  if (v3.x != 0.f) pm |= 1 << 12;
  if (v3.y != 0.f) pm |= 1 << 13;
  if (v3.z != 0.f) pm |= 1 << 14;
  if (v3.w != 0.f) pm |= 1 << 15;
  const int cnt = __popc(pm);

  int pfx = cnt;
#pragma unroll
  for (int off = 1; off < 64; off <<= 1) {
    const int o = __shfl_up(pfx, off);
    if (lane >= off) pfx += o;
  }
  if (lane == 63) wsum[wave] = pfx;
  __syncthreads();

  int base = 0;
#pragma unroll
  for (int w = 0; w < 4; ++w)
    if (w < wave) base += wsum[w];
  const int total = wsum[0] + wsum[1] + wsum[2] + wsum[3];
  const int count = total < CAP ? total : CAP;

  {
    int pos = base + pfx - cnt;
    unsigned m = (unsigned)pm;
    while (m) {
      const int b = __builtin_ctz(m);
      m &= m - 1;
      if (pos < CAP) cols[pos] = ((b >> 2) << 10) + (tid << 2) + (b & 3);
      ++pos;
    }
  }
  __syncthreads();

  // ---- phase 2: scores for all 8 heads (count <= 128 -> 1 iteration) ----
  float asrc[HH];
#pragma unroll
  for (int h = 0; h < HH; ++h) asrc[h] = a_src[(size_t)h * NN + i];

  for (int t = tid; t < count; t += 256) {
    const int c = cols[t];
    const float b = 0.01f * brow[c];
    const float4 d0 = *reinterpret_cast<const float4*>(&a_dstT[(size_t)c * HH]);
    const float4 d1 = *reinterpret_cast<const float4*>(&a_dstT[(size_t)c * HH + 4]);
    float s;
    s = asrc[0] + d0.x + b; att[0][t] = (s >= 0.f) ? s : 0.2f * s;
    s = asrc[1] + d0.y + b; att[1][t] = (s >= 0.f) ? s : 0.2f * s;
    s = asrc[2] + d0.z + b; att[2][t] = (s >= 0.f) ? s : 0.2f * s;
    s = asrc[3] + d0.w + b; att[3][t] = (s >= 0.f) ? s : 0.2f * s;
    s = asrc[4] + d1.x + b; att[4][t] = (s >= 0.f) ? s : 0.2f * s;
    s = asrc[5] + d1.y + b; att[5][t] = (s >= 0.f) ? s : 0.2f * s;
    s = asrc[6] + d1.z + b; att[6][t] = (s >= 0.f) ? s : 0.2f * s;
    s = asrc[7] + d1.w + b; att[7][t] = (s >= 0.f) ? s : 0.2f * s;
  }
  __syncthreads();

  // ---- phase 3: softmax; 32-lane group g owns head g ----
  {
    const int g = tid >> 5;
    const int l = tid & 31;
    float* arow_h = att[g];
    float m = -3.0e38f;
    for (int t = l; t < count; t += 32) m = fmaxf(m, arow_h[t]);
#pragma unroll
    for (int o = 16; o >= 1; o >>= 1) m = fmaxf(m, __shfl_xor(m, o));
    float ssum = 0.f;
    for (int t = l; t < count; t += 32) {
      const float e = expf(arow_h[t] - m);
      arow_h[t] = e;
      ssum += e;
    }
#pragma unroll
    for (int o = 16; o >= 1; o >>= 1) ssum += __shfl_xor(ssum, o);
    const float inv = 1.0f / ssum;
    for (int t = l; t < count; t += 32) arow_h[t] *= inv;
  }
  __syncthreads();

  // ---- phase 4: wave w owns outputs [128w, 128w+128); lane owns 2 floats ----
  {
    const int o0 = (wave << 7) + (lane << 1);
    const int h = o0 >> 6;
    const float* attrow = att[h];
    const unsigned short* hb = hiddenT + o0;
    float s0 = 0.f, s1 = 0.f;
    int t = 0;
    for (; t + 4 <= count; t += 4) {
      const int4 c4 = *reinterpret_cast<const int4*>(&cols[t]);
      const float4 a4 = *reinterpret_cast<const float4*>(&attrow[t]);
      const ushort2 u0 = *reinterpret_cast<const ushort2*>(hb + (size_t)c4.x * (HH * RR));
      const ushort2 u1 = *reinterpret_cast<const ushort2*>(hb + (size_t)c4.y * (HH * RR));
      const ushort2 u2 = *reinterpret_cast<const ushort2*>(hb + (size_t)c4.z * (HH * RR));
      const ushort2 u3 = *reinterpret_cast<const ushort2*>(hb + (size_t)c4.w * (HH * RR));
      s0 += a4.x * bf2f(u0.x); s1 += a4.x * bf2f(u0.y);
      s0 += a4.y * bf2f(u1.x); s1 += a4.y * bf2f(u1.y);
      s0 += a4.z * bf2f(u2.x); s1 += a4.z * bf2f(u2.y);
      s0 += a4.w * bf2f(u3.x); s1 += a4.w * bf2f(u3.y);
    }
    for (; t < count; ++t) {
      const int c = cols[t];
      const float a = attrow[t];
      const ushort2 u = *reinterpret_cast<const ushort2*>(hb + (size_t)c * (HH * RR));
      s0 += a * bf2f(u.x); s1 += a * bf2f(u.y);
    }
    float2 r = make_float2(s0, s1);
    *reinterpret_cast<float2*>(&out[(size_t)i * (HH * RR) + o0]) = r;
  }
}

extern "C" void kernel_launch(void* const* d_in, const int* in_sizes, int n_in,
                              void* d_out, int out_size, void* d_ws, size_t ws_size,
                              hipStream_t stream) {
  const float* X    = (const float*)d_in[0];   // [N,F]
  const float* adj  = (const float*)d_in[1];   // [N,N]
  const float* W    = (const float*)d_in[2];   // [H,F,R]
  const float* sa   = (const float*)d_in[3];   // [H,2R]
  const float* bias = (const float*)d_in[4];   // [N,N]
  float* out = (float*)d_out;                  // [N, H*R]

  unsigned short* hiddenT = (unsigned short*)d_ws;            // [N][H*R] bf16, 4 MB
  float* a_src  = (float*)(hiddenT + (size_t)NN * HH * RR);   // [H][N], 128 KB
  float* a_dstT = a_src + (size_t)HH * NN;                    // [N][H], 128 KB

  k_gemm_hidden<<<dim3(NN / 64, HH), 256, 0, stream>>>(X, W, sa, hiddenT, a_src, a_dstT);
  k_gat_row<<<dim3(NN), 256, 0, stream>>>(adj, bias, a_src, a_dstT, hiddenT, out);
}

// Round 5
// 52.747 us; speedup vs baseline: 2.1424x; 1.2763x over previous
//
#include <hip/hip_runtime.h>
#include <hip/hip_bf16.h>

#define NN 4096
#define FF 512
#define RR 64
#define HH 8
#define HR (HH * RR)     // 512
#define CAP 128
#define ATT_STRIDE 144   // group offset 16 mod 32 -> 2-way (free) in softmax

typedef short bf16x8 __attribute__((ext_vector_type(8)));
typedef float f32x4 __attribute__((ext_vector_type(4)));

__device__ __forceinline__ unsigned short f2bf(float f) {
  __hip_bfloat16 h = __float2bfloat16(f);   // RNE
  return *reinterpret_cast<unsigned short*>(&h);
}
__device__ __forceinline__ float bf2f(unsigned short u) {
  union { unsigned u32; float f; } cv;
  cv.u32 = ((unsigned)u) << 16;
  return cv.f;
}

// ---------------------------------------------------------------------------
// K0: Xb[n][f] = bf16(X[n][f]);  BbT[(h*64+r)][f] = bf16(W[h][f][r])
// X part: 524288 threads x float4.  W part: 262144 threads, coalesced writes.
// ---------------------------------------------------------------------------
__global__ __launch_bounds__(256) void k_convert(
    const float* __restrict__ X, const float* __restrict__ W,
    unsigned short* __restrict__ Xb, unsigned short* __restrict__ BbT)
{
  const int t = blockIdx.x * 256 + threadIdx.x;
  if (t < 524288) {
    const float4 v = reinterpret_cast<const float4*>(X)[t];
    ushort4 u;
    u.x = f2bf(v.x); u.y = f2bf(v.y); u.z = f2bf(v.z); u.w = f2bf(v.w);
    reinterpret_cast<ushort4*>(Xb)[t] = u;
  } else {
    const int o = t - 524288;          // 0..262143
    const int n = o >> 9;              // (h*64+r)
    const int f = o & 511;
    const int h = n >> 6, r = n & 63;
    BbT[(size_t)n * FF + f] = f2bf(W[(size_t)h * FF * RR + (size_t)f * RR + r]);
  }
}

// ---------------------------------------------------------------------------
// K1: hiddenT[m][n] = sum_k Xb[m][k] * BbT[n][k]   (M=4096, N=512, K=512)
// 64x64 tile, 256 thr = 4 waves, wave (wr,wc) owns 32x32 via 2x2 16x16x32 MFMA.
// ---------------------------------------------------------------------------
__global__ __launch_bounds__(256) void k_gemm_hidden(
    const unsigned short* __restrict__ Xb,
    const unsigned short* __restrict__ BbT,
    unsigned short* __restrict__ hiddenT)
{
  const int row0 = blockIdx.x * 64;   // M
  const int n0 = blockIdx.y * 64;     // N
  __shared__ unsigned short Als[64 * 32];  // [m][k], row stride 32 elts (64 B)
  __shared__ unsigned short Bls[64 * 32];  // [n][k]
  const int tid = threadIdx.x;
  const int l = tid & 63;
  const int wid = tid >> 6;
  const int wr = wid >> 1, wc = wid & 1;

  f32x4 acc[2][2];
#pragma unroll
  for (int a = 0; a < 2; ++a)
#pragma unroll
    for (int b = 0; b < 2; ++b) acc[a][b] = (f32x4){0.f, 0.f, 0.f, 0.f};

  const int srow = tid >> 2;           // 0..63
  const int skel = (tid & 3) * 8;      // k element 0,8,16,24

  for (int k0 = 0; k0 < FF; k0 += 32) {
    const int4 av = *reinterpret_cast<const int4*>(
        &Xb[(size_t)(row0 + srow) * FF + k0 + skel]);
    const int4 bv = *reinterpret_cast<const int4*>(
        &BbT[(size_t)(n0 + srow) * FF + k0 + skel]);
    __syncthreads();
    *reinterpret_cast<int4*>(&Als[tid * 8]) = av;   // linear: tid*16 bytes
    *reinterpret_cast<int4*>(&Bls[tid * 8]) = bv;
    __syncthreads();

    const int ka = (l >> 4) * 8;   // k offset for this lane group
    const bf16x8 a0 = *reinterpret_cast<const bf16x8*>(&Als[(32 * wr + 0  + (l & 15)) * 32 + ka]);
    const bf16x8 a1 = *reinterpret_cast<const bf16x8*>(&Als[(32 * wr + 16 + (l & 15)) * 32 + ka]);
    const bf16x8 b0 = *reinterpret_cast<const bf16x8*>(&Bls[(32 * wc + 0  + (l & 15)) * 32 + ka]);
    const bf16x8 b1 = *reinterpret_cast<const bf16x8*>(&Bls[(32 * wc + 16 + (l & 15)) * 32 + ka]);
    acc[0][0] = __builtin_amdgcn_mfma_f32_16x16x32_bf16(a0, b0, acc[0][0], 0, 0, 0);
    acc[0][1] = __builtin_amdgcn_mfma_f32_16x16x32_bf16(a0, b1, acc[0][1], 0, 0, 0);
    acc[1][0] = __builtin_amdgcn_mfma_f32_16x16x32_bf16(a1, b0, acc[1][0], 0, 0, 0);
    acc[1][1] = __builtin_amdgcn_mfma_f32_16x16x32_bf16(a1, b1, acc[1][1], 0, 0, 0);
  }

  // epilogue: C/D layout col=l&15, row=(l>>4)*4+j  (m89-verified)
#pragma unroll
  for (int mi = 0; mi < 2; ++mi)
#pragma unroll
    for (int ni = 0; ni < 2; ++ni)
#pragma unroll
      for (int j = 0; j < 4; ++j) {
        const int rowg = row0 + 32 * wr + 16 * mi + ((l >> 4) << 2) + j;
        const int colg = n0 + 32 * wc + 16 * ni + (l & 15);
        hiddenT[(size_t)rowg * HR + colg] = f2bf(acc[mi][ni][j]);
      }
}

// ---------------------------------------------------------------------------
// K2: a_src[h][n] = hiddenT[n][h*64+:64] . sa[h][0:64];  a_dstT[n][h] likewise
// ---------------------------------------------------------------------------
__global__ __launch_bounds__(256) void k_src_dst(
    const unsigned short* __restrict__ hiddenT,
    const float* __restrict__ sa,
    float* __restrict__ a_src,
    float* __restrict__ a_dstT)
{
  const int idx = blockIdx.x * 256 + threadIdx.x;  // 0..32767
  const int h = idx & 7;
  const int n = idx >> 3;
  const unsigned short* hp = hiddenT + (size_t)n * HR + h * RR;
  const float* ss = sa + (size_t)h * 2 * RR;
  const float* sd = ss + RR;
  float s = 0.f, d = 0.f;
#pragma unroll
  for (int v = 0; v < 16; ++v) {
    const ushort4 u = reinterpret_cast<const ushort4*>(hp)[v];
    const float4 sv = reinterpret_cast<const float4*>(ss)[v];
    const float4 dv = reinterpret_cast<const float4*>(sd)[v];
    const float x0 = bf2f(u.x), x1 = bf2f(u.y), x2 = bf2f(u.z), x3 = bf2f(u.w);
    s += x0 * sv.x + x1 * sv.y + x2 * sv.z + x3 * sv.w;
    d += x0 * dv.x + x1 * dv.y + x2 * dv.z + x3 * dv.w;
  }
  a_src[(size_t)h * NN + n] = s;
  a_dstT[(size_t)n * HH + h] = d;
}

__device__ __forceinline__ unsigned nib4(const float4 v) {
  unsigned m = 0;
  if (v.x != 0.f) m |= 1u;
  if (v.y != 0.f) m |= 2u;
  if (v.z != 0.f) m |= 4u;
  if (v.w != 0.f) m |= 8u;
  return m;
}

// ---------------------------------------------------------------------------
// K3: ONE 128-thread block (2 waves) per row; grid 4096 -> 16 blocks/CU, the
// whole kernel co-resident (wave-slot limit). 8 float4 adj loads in flight.
// ---------------------------------------------------------------------------
__global__ __launch_bounds__(128) void k_gat_row(
    const float* __restrict__ adj,
    const float* __restrict__ bias,
    const float* __restrict__ a_src,
    const float* __restrict__ a_dstT,
    const unsigned short* __restrict__ hiddenT,
    float* __restrict__ out)
{
  const int i = blockIdx.x;
  const int tid = threadIdx.x;
  const int lane = tid & 63;
  const int wave = tid >> 6;

  __shared__ __align__(16) float att[HH][ATT_STRIDE];
  __shared__ int cols[CAP];
  __shared__ int wsum[2];

  const float* arow = adj + (size_t)i * NN;
  const float* brow = bias + (size_t)i * NN;

  float asrc[HH];
#pragma unroll
  for (int h = 0; h < HH; ++h) asrc[h] = a_src[(size_t)h * NN + i];

  // ---- phase 1: 8 float4 loads (all in flight) + one block prefix-sum ----
  float4 buf[8];
#pragma unroll
  for (int c = 0; c < 8; ++c)
    buf[c] = *reinterpret_cast<const float4*>(&arow[c * 512 + (tid << 2)]);
  unsigned pm = 0;
#pragma unroll
  for (int c = 0; c < 8; ++c) pm |= nib4(buf[c]) << (4 * c);
  const int cnt = __popc(pm);

  int pfx = cnt;
#pragma unroll
  for (int off = 1; off < 64; off <<= 1) {
    const int o = __shfl_up(pfx, off);
    if (lane >= off) pfx += o;
  }
  if (lane == 63) wsum[wave] = pfx;
  __syncthreads();

  const int base = (wave == 1) ? wsum[0] : 0;
  const int total = wsum[0] + wsum[1];
  const int count = total < CAP ? total : CAP;

  {
    int pos = base + pfx - cnt;
    unsigned m = pm;
    while (m) {
      const int b = __builtin_ctz(m);
      m &= m - 1;
      if (pos < CAP) cols[pos] = ((b >> 2) << 9) + (tid << 2) + (b & 3);
      ++pos;
    }
  }
  __syncthreads();

  // ---- phase 2: scores for all 8 heads (count <= 128 -> 1 iteration) ----
  if (tid < count) {
    const int c = cols[tid];
    const float b = 0.01f * brow[c];
    const float4 d0 = *reinterpret_cast<const float4*>(&a_dstT[(size_t)c * HH]);
    const float4 d1 = *reinterpret_cast<const float4*>(&a_dstT[(size_t)c * HH + 4]);
    float s;
    s = asrc[0] + d0.x + b; att[0][tid] = (s >= 0.f) ? s : 0.2f * s;
    s = asrc[1] + d0.y + b; att[1][tid] = (s >= 0.f) ? s : 0.2f * s;
    s = asrc[2] + d0.z + b; att[2][tid] = (s >= 0.f) ? s : 0.2f * s;
    s = asrc[3] + d0.w + b; att[3][tid] = (s >= 0.f) ? s : 0.2f * s;
    s = asrc[4] + d1.x + b; att[4][tid] = (s >= 0.f) ? s : 0.2f * s;
    s = asrc[5] + d1.y + b; att[5][tid] = (s >= 0.f) ? s : 0.2f * s;
    s = asrc[6] + d1.z + b; att[6][tid] = (s >= 0.f) ? s : 0.2f * s;
    s = asrc[7] + d1.w + b; att[7][tid] = (s >= 0.f) ? s : 0.2f * s;
  }
  __syncthreads();

  // ---- phase 3: softmax; 16-lane group g = tid>>4 owns head g ----
  {
    const int g = tid >> 4;
    const int l16 = tid & 15;
    float* arow_h = att[g];
    float m = -3.0e38f;
    for (int t = l16; t < count; t += 16) m = fmaxf(m, arow_h[t]);
#pragma unroll
    for (int o = 8; o >= 1; o >>= 1) m = fmaxf(m, __shfl_xor(m, o));
    float ssum = 0.f;
    for (int t = l16; t < count; t += 16) {
      const float e = expf(arow_h[t] - m);
      arow_h[t] = e;
      ssum += e;
    }
#pragma unroll
    for (int o = 8; o >= 1; o >>= 1) ssum += __shfl_xor(ssum, o);
    const float inv = 1.0f / ssum;
    for (int t = l16; t < count; t += 16) arow_h[t] *= inv;
  }
  __syncthreads();

  // ---- phase 4: thread owns 4 outputs at o0 = tid*4; h = tid>>4 ----
  {
    const int o0 = tid << 2;
    const float* attrow = att[tid >> 4];
    const unsigned short* hb = hiddenT + o0;
    float4 acc = make_float4(0.f, 0.f, 0.f, 0.f);
    int t = 0;
    for (; t + 4 <= count; t += 4) {
      const int4 c4 = *reinterpret_cast<const int4*>(&cols[t]);
      const float4 a4 = *reinterpret_cast<const float4*>(&attrow[t]);
#pragma unroll
      for (int j = 0; j < 4; ++j) {
        const int c = (j == 0) ? c4.x : (j == 1) ? c4.y : (j == 2) ? c4.z : c4.w;
        const float a = (j == 0) ? a4.x : (j == 1) ? a4.y : (j == 2) ? a4.z : a4.w;
        const ushort4 u = *reinterpret_cast<const ushort4*>(hb + (size_t)c * HR);
        acc.x += a * bf2f(u.x); acc.y += a * bf2f(u.y);
        acc.z += a * bf2f(u.z); acc.w += a * bf2f(u.w);
      }
    }
    for (; t < count; ++t) {
      const int c = cols[t];
      const float a = attrow[t];
      const ushort4 u = *reinterpret_cast<const ushort4*>(hb + (size_t)c * HR);
      acc.x += a * bf2f(u.x); acc.y += a * bf2f(u.y);
      acc.z += a * bf2f(u.z); acc.w += a * bf2f(u.w);
    }
    *reinterpret_cast<float4*>(&out[(size_t)i * HR + o0]) = acc;
  }
}

extern "C" void kernel_launch(void* const* d_in, const int* in_sizes, int n_in,
                              void* d_out, int out_size, void* d_ws, size_t ws_size,
                              hipStream_t stream) {
  const float* X    = (const float*)d_in[0];   // [N,F]
  const float* adj  = (const float*)d_in[1];   // [N,N]
  const float* W    = (const float*)d_in[2];   // [H,F,R]
  const float* sa   = (const float*)d_in[3];   // [H,2R]
  const float* bias = (const float*)d_in[4];   // [N,N]
  float* out = (float*)d_out;                  // [N, H*R]

  unsigned short* hiddenT = (unsigned short*)d_ws;        // [N][512] bf16, 4 MB
  unsigned short* Xb  = hiddenT + (size_t)NN * HR;        // [N][512] bf16, 4 MB
  unsigned short* BbT = Xb + (size_t)NN * FF;             // [512][512] bf16, 512 KB
  float* a_src  = (float*)(BbT + (size_t)HR * FF);        // [H][N], 128 KB
  float* a_dstT = a_src + (size_t)HH * NN;                // [N][H], 128 KB

  k_convert<<<dim3(3072), 256, 0, stream>>>(X, W, Xb, BbT);
  k_gemm_hidden<<<dim3(NN / 64, HR / 64), 256, 0, stream>>>(Xb, BbT, hiddenT);
  k_src_dst<<<dim3(128), 256, 0, stream>>>(hiddenT, sa, a_src, a_dstT);
  k_gat_row<<<dim3(NN), 128, 0, stream>>>(adj, bias, a_src, a_dstT, hiddenT, out);
}